// Round 6
// baseline (14303.778 us; speedup 1.0000x reference)
//
#include <hip/hip_runtime.h>

typedef _Float16 h8 __attribute__((ext_vector_type(8)));
typedef float    f4 __attribute__((ext_vector_type(4)));

// ---------------- workspace layout (bytes) ----------------
// hbuf32 : 2*8*8*512 fp32 = 262,144  [parity][ig 8][row 8][unit 512]
//          each dword: fp32 h with 10-bit step tag in mantissa LSBs
static const unsigned long long OFF_HBUF  = 0ull;
static const unsigned long long WS_NEEDED = 262144ull;

__device__ __forceinline__ float sigm(float x)   { return 1.0f / (1.0f + __expf(-x)); }
__device__ __forceinline__ float tanh_a(float x) { return 2.0f / (1.0f + __expf(-2.0f * x)) - 1.0f; }

__device__ __forceinline__ h8 cvt2(f4 a0, f4 a1)
{
    h8 a;
    a[0] = (_Float16)a0[0]; a[1] = (_Float16)a0[1];
    a[2] = (_Float16)a0[2]; a[3] = (_Float16)a0[3];
    a[4] = (_Float16)a1[0]; a[5] = (_Float16)a1[1];
    a[6] = (_Float16)a1[2]; a[7] = (_Float16)a1[3];
    return a;
}

// ---------------- k_init: fill h buffer with tag=1023, value~0 ----------------
// 0x000003FF = denormal fp32 (~1.4e-42, cvt to fp16 -> 0) carrying tag 1023,
// which is the expected tag at t=0 (parity 1) and a non-matching tag for the
// parity-0 slot first read at t=1 (expected tag 0).
__global__ __launch_bounds__(256) void k_init(unsigned* hbuf)
{
    const int idx = blockIdx.x * 256 + threadIdx.x;
    if (idx < 65536) hbuf[idx] = 0x000003FFu;
}

// ---------------- k_rec: persistent fused LSTM, flagless tag protocol ----------------
// 64 blocks = 8 batch-groups (ig) x 8 unit-groups (jg: 64 units). U,V in
// VGPRs as MFMA fragments. ROUND-6 LESSON CHAIN: R3/R4/R5 showed the only
// effective lever is removing dependent MALL round trips from the per-step
// serial chain (flag scheme = 4 trips: drain, flag store, poll, h load).
// This version embeds a 10-bit step tag in each published fp32 h dword:
// producers never wait (no drain/flag/fence), consumers' data loads ARE the
// poll (retry until all 128 tags match). ~1.5 dependent trips per step.
__global__ __launch_bounds__(256, 1) void k_rec(
    const float* __restrict__ x,
    const float* __restrict__ Ui, const float* __restrict__ Vi, const float* __restrict__ bi,
    const float* __restrict__ Uf, const float* __restrict__ Vf, const float* __restrict__ bf,
    const float* __restrict__ Uh, const float* __restrict__ Vh, const float* __restrict__ bh,
    const float* __restrict__ Uo, const float* __restrict__ Vo, const float* __restrict__ bo,
    unsigned* hbuf)
{
    const int bx = blockIdx.x;
    const int ig = bx & 7;      // bx&7 -> XCD-affine team (perf heuristic only)
    const int jg = bx >> 3;
    const int tid = threadIdx.x;
    const int w = tid >> 6, l = tid & 63;
    const int lo = l & 15, hi = l >> 4;
    const int unit = jg * 64 + w * 16 + lo;          // hidden unit [0,512)

    const float* Ug[4] = {Ui, Uf, Uh, Uo};
    const float* Vg[4] = {Vi, Vf, Vh, Vo};
    const float* bg[4] = {bi, bf, bh, bo};

    // ---- one-time fragment preload (fp32 -> fp16 cvt) ----
    // B-frag (16x16x32): lane holds B[k = kc*32 + hi*8 + jj][n = lo]
    h8 vfrag[4][16];   // V: K=512 -> 16 k-chunks   (256 VGPRs)
    h8 ufrag[4][8];    // U: K=256 ->  8 k-chunks   (128 VGPRs)
    float bias[4];
#pragma unroll
    for (int g = 0; g < 4; ++g) {
        bias[g] = bg[g][unit];
#pragma unroll
        for (int kc = 0; kc < 16; ++kc) {
            h8 v;
#pragma unroll
            for (int jj = 0; jj < 8; ++jj)
                v[jj] = (_Float16)Vg[g][(size_t)(kc * 32 + hi * 8 + jj) * 512 + unit];
            vfrag[g][kc] = v;
        }
#pragma unroll
        for (int kc = 0; kc < 8; ++kc) {
            h8 u;
#pragma unroll
            for (int jj = 0; jj < 8; ++jj)
                u[jj] = (_Float16)Ug[g][(size_t)(kc * 32 + hi * 8 + jj) * 512 + unit];
            ufrag[g][kc] = u;
        }
    }

    // A-frag row m = lo; batch row = ig*8 + (lo&7) (rows 8..15 duplicate)
    const float* xb = x + (size_t)(ig * 8 + (lo & 7)) * 262144 + hi * 8;
    f4 cst = {0.f, 0.f, 0.f, 0.f};   // cell state, C-layout rows hi*4+d

    for (int t = 0; t < 1024; ++t) {
        const int pr = (t + 1) & 1, pw = t & 1;
        const unsigned etag = (unsigned)((t + 1023) & 1023);   // tag of h_{t-1}

        // ---- x_t load + cvt (latency absorbed by the exchange retry slack) ----
        const float* xt = xb + (size_t)t * 256;
        h8 xa[8];
        {
            f4 xr[16];
#pragma unroll
            for (int i = 0; i < 8; ++i) {
                xr[2 * i]     = *(const f4*)(xt + i * 32);
                xr[2 * i + 1] = *(const f4*)(xt + i * 32 + 4);
            }
#pragma unroll
            for (int i = 0; i < 8; ++i) xa[i] = cvt2(xr[2 * i], xr[2 * i + 1]);
        }

        // ---- gate-init: bias + x_t @ U ----
        f4 acc[4];
#pragma unroll
        for (int g = 0; g < 4; ++g) {
            f4 a; a[0] = bias[g]; a[1] = bias[g]; a[2] = bias[g]; a[3] = bias[g];
            acc[g] = a;
        }
#pragma unroll
        for (int kc = 0; kc < 8; ++kc) {
            acc[0] = __builtin_amdgcn_mfma_f32_16x16x32_f16(xa[kc], ufrag[0][kc], acc[0], 0, 0, 0);
            acc[1] = __builtin_amdgcn_mfma_f32_16x16x32_f16(xa[kc], ufrag[1][kc], acc[1], 0, 0, 0);
            acc[2] = __builtin_amdgcn_mfma_f32_16x16x32_f16(xa[kc], ufrag[2][kc], acc[2], 0, 0, 0);
            acc[3] = __builtin_amdgcn_mfma_f32_16x16x32_f16(xa[kc], ufrag[3][kc], acc[3], 0, 0, 0);
        }

        // ---- h exchange: tagged atomic loads, retry until all tags == etag ----
        // lane's span: row (lo&7), dwords [hi*8 .. hi*8+8) within each kc*32
        const unsigned long long* hp = (const unsigned long long*)
            (hbuf + (size_t)((pr * 8 + ig) * 8 + (lo & 7)) * 512 + hi * 8);
        unsigned long long q[64];
        unsigned err;
        do {
#pragma unroll
            for (int kc = 0; kc < 16; ++kc) {
#pragma unroll
                for (int a2 = 0; a2 < 4; ++a2)
                    q[kc * 4 + a2] = __hip_atomic_load(hp + kc * 16 + a2,
                                                       __ATOMIC_RELAXED, __HIP_MEMORY_SCOPE_AGENT);
            }
            err = 0u;
#pragma unroll
            for (int i = 0; i < 64; ++i) {
                union { unsigned long long q; unsigned u[2]; } v; v.q = q[i];
                err |= (v.u[0] ^ etag) & 1023u;
                err |= (v.u[1] ^ etag) & 1023u;
            }
        } while (err != 0u);

        // ---- h_{t-1} @ V (tag bits are below fp16 rounding; cvt directly) ----
#pragma unroll
        for (int kc = 0; kc < 16; ++kc) {
            union { unsigned long long q; unsigned u[2]; } v0, v1, v2, v3;
            v0.q = q[kc * 4 + 0]; v1.q = q[kc * 4 + 1];
            v2.q = q[kc * 4 + 2]; v3.q = q[kc * 4 + 3];
            h8 a;
            a[0] = (_Float16)__uint_as_float(v0.u[0]); a[1] = (_Float16)__uint_as_float(v0.u[1]);
            a[2] = (_Float16)__uint_as_float(v1.u[0]); a[3] = (_Float16)__uint_as_float(v1.u[1]);
            a[4] = (_Float16)__uint_as_float(v2.u[0]); a[5] = (_Float16)__uint_as_float(v2.u[1]);
            a[6] = (_Float16)__uint_as_float(v3.u[0]); a[7] = (_Float16)__uint_as_float(v3.u[1]);
            acc[0] = __builtin_amdgcn_mfma_f32_16x16x32_f16(a, vfrag[0][kc], acc[0], 0, 0, 0);
            acc[1] = __builtin_amdgcn_mfma_f32_16x16x32_f16(a, vfrag[1][kc], acc[1], 0, 0, 0);
            acc[2] = __builtin_amdgcn_mfma_f32_16x16x32_f16(a, vfrag[2][kc], acc[2], 0, 0, 0);
            acc[3] = __builtin_amdgcn_mfma_f32_16x16x32_f16(a, vfrag[3][kc], acc[3], 0, 0, 0);
        }

        // ---- elementwise (C rows hi*4+d; rows 8..15 are pad, not stored) ----
        const unsigned ptag = (unsigned)(t & 1023);
        unsigned pub[4];
#pragma unroll
        for (int d = 0; d < 4; ++d) {
            const float iv = sigm(acc[0][d]);
            const float fv = sigm(acc[1][d]);
            const float gv = tanh_a(acc[2][d]);
            const float ov = sigm(acc[3][d]);
            const float c = fv * cst[d] + iv * gv;
            cst[d] = c;
            const float hv = ov * tanh_a(c);
            pub[d] = (__float_as_uint(hv) & 0xFFFFFC00u) | ptag;
        }
        // ---- publish: tagged 4B atomic stores, fire-and-forget ----
        if (hi < 2) {
            unsigned* hw = hbuf + (size_t)((pw * 8 + ig) * 8 + hi * 4) * 512 + unit;
#pragma unroll
            for (int d = 0; d < 4; ++d)
                __hip_atomic_store(hw + (size_t)d * 512, pub[d],
                                   __ATOMIC_RELAXED, __HIP_MEMORY_SCOPE_AGENT);
        }
    }
}

// ---------------- k_fc: out[b] = h_last[b,:] . fc_w + fc_b ----------------
__global__ __launch_bounds__(64) void k_fc(
    const unsigned* __restrict__ hbuf, const float* __restrict__ fcw,
    const float* __restrict__ fcb, float* __restrict__ out)
{
    const int b = blockIdx.x, l = threadIdx.x;
    // h_1023 lives at parity 1; ig = b>>3, row = b&7; mask the tag bits
    const unsigned* h = hbuf + (size_t)((8 + (b >> 3)) * 8 + (b & 7)) * 512;
    float s = 0.f;
#pragma unroll
    for (int k = 0; k < 8; ++k) {
        const float hv = __uint_as_float(h[l + k * 64] & 0xFFFFFC00u);
        s += hv * fcw[l + k * 64];
    }
    for (int off = 32; off > 0; off >>= 1) s += __shfl_down(s, off, 64);
    if (l == 0) out[b] = s + fcb[0];
}

__global__ __launch_bounds__(64) void k_sentinel(float* out)
{
    out[threadIdx.x] = -777777.0f;   // signature: ws_size too small
}

extern "C" void kernel_launch(void* const* d_in, const int* in_sizes, int n_in,
                              void* d_out, int out_size, void* d_ws, size_t ws_size,
                              hipStream_t stream)
{
    const float* x   = (const float*)d_in[0];
    const float* Ui  = (const float*)d_in[1];
    const float* Vi  = (const float*)d_in[2];
    const float* bi  = (const float*)d_in[3];
    const float* Uf  = (const float*)d_in[4];
    const float* Vf  = (const float*)d_in[5];
    const float* bf  = (const float*)d_in[6];
    const float* Uh  = (const float*)d_in[7];
    const float* Vh  = (const float*)d_in[8];
    const float* bh  = (const float*)d_in[9];
    const float* Uo  = (const float*)d_in[10];
    const float* Vo  = (const float*)d_in[11];
    const float* bo  = (const float*)d_in[12];
    const float* fcw = (const float*)d_in[13];
    const float* fcb = (const float*)d_in[14];
    float* out = (float*)d_out;

    if (ws_size < WS_NEEDED) {
        k_sentinel<<<1, 64, 0, stream>>>(out);
        return;
    }

    unsigned* hbuf = (unsigned*)((char*)d_ws + OFF_HBUF);

    k_init<<<256, 256, 0, stream>>>(hbuf);
    k_rec <<<64,  256, 0, stream>>>(x, Ui, Vi, bi, Uf, Vf, bf, Uh, Vh, bh,
                                    Uo, Vo, bo, hbuf);
    k_fc  <<<64,   64, 0, stream>>>(hbuf, fcw, fcb, out);
}

// Round 7
// 3290.282 us; speedup vs baseline: 4.3473x; 4.3473x over previous
//
#include <hip/hip_runtime.h>

typedef _Float16 h8 __attribute__((ext_vector_type(8)));
typedef float    f4 __attribute__((ext_vector_type(4)));

// ---------------- workspace layout (bytes) ----------------
// hbuf32 : 2*8*8*512 fp32 = 262,144  [parity][ig 8][row 8][unit 512]
//          each dword: fp32 h with 10-bit step tag in mantissa LSBs
static const unsigned long long OFF_HBUF  = 0ull;
static const unsigned long long WS_NEEDED = 262144ull;

__device__ __forceinline__ float sigm(float x)   { return 1.0f / (1.0f + __expf(-x)); }
__device__ __forceinline__ float tanh_a(float x) { return 2.0f / (1.0f + __expf(-2.0f * x)) - 1.0f; }

// ---------------- k_init: fill h buffer with tag=1023, value~0 ----------------
// 0x000003FF = denormal fp32 (~1.4e-42 -> fp16 0) carrying tag 1023 = expected
// tag at t=0; non-matching for the parity-0 slot first read at t=1 (tag 0).
__global__ __launch_bounds__(256) void k_init(unsigned* hbuf)
{
    const int idx = blockIdx.x * 256 + threadIdx.x;
    if (idx < 65536) hbuf[idx] = 0x000003FFu;
}

// ---------------- k_rec: persistent fused LSTM, tag protocol + LDS staging ----------------
// 64 blocks = 8 batch-groups (ig) x 8 unit-groups (jg: 64 units). U,V in
// VGPRs/AGPRs as MFMA fragments.
// R7 LESSON CHAIN: R2-R6 protocols all ~9-14 ms because every lane
// individually bypass-loaded its 512 B h-span (4096 scattered bypass loads
// per block per step -> ~250k MALL line transactions/step device-wide).
// Fix: ONE coalesced cooperative staging pass per block (16 KB unique data,
// lane-contiguous 8 B bypass loads), tag-consensus, then LDS fragment reads.
// x_{t+1} prefetched (R4's proven lever) through LDS, keeping registers <512.
__global__ __launch_bounds__(256, 1) void k_rec(
    const float* __restrict__ x,
    const float* __restrict__ Ui, const float* __restrict__ Vi, const float* __restrict__ bi,
    const float* __restrict__ Uf, const float* __restrict__ Vf, const float* __restrict__ bf,
    const float* __restrict__ Uh, const float* __restrict__ Vh, const float* __restrict__ bh,
    const float* __restrict__ Uo, const float* __restrict__ Vo, const float* __restrict__ bo,
    unsigned* hbuf)
{
    const int bx = blockIdx.x;
    const int ig = bx & 7;      // bx&7 -> XCD-affine team (perf heuristic only)
    const int jg = bx >> 3;
    const int tid = threadIdx.x;
    const int w = tid >> 6, l = tid & 63;
    const int lo = l & 15, hi = l >> 4;
    const int r8 = lo & 7;                           // batch row within group
    const int unit = jg * 64 + w * 16 + lo;          // hidden unit [0,512)

    // LDS: h fragments [kc 16][g=hi*8+row 32][8 fp16] = 8 KB
    //      x fragments [kc  8][g 32][8 fp16]          = 4 KB
    __shared__ __align__(16) _Float16 ldsH[16 * 32 * 8];
    __shared__ __align__(16) _Float16 ldsX[8 * 32 * 8];
    __shared__ unsigned s_err[4];

    const float* Ug[4] = {Ui, Uf, Uh, Uo};
    const float* Vg[4] = {Vi, Vf, Vh, Vo};
    const float* bg[4] = {bi, bf, bh, bo};

    // ---- one-time fragment preload (fp32 -> fp16 cvt) ----
    // B-frag (16x16x32): lane holds B[k = kc*32 + hi*8 + jj][n = lo]
    h8 vfrag[4][16];   // V: K=512 -> 16 k-chunks
    h8 ufrag[4][8];    // U: K=256 ->  8 k-chunks
    float bias[4];
#pragma unroll
    for (int g = 0; g < 4; ++g) {
        bias[g] = bg[g][unit];
#pragma unroll
        for (int kc = 0; kc < 16; ++kc) {
            h8 v;
#pragma unroll
            for (int jj = 0; jj < 8; ++jj)
                v[jj] = (_Float16)Vg[g][(size_t)(kc * 32 + hi * 8 + jj) * 512 + unit];
            vfrag[g][kc] = v;
        }
#pragma unroll
        for (int kc = 0; kc < 8; ++kc) {
            h8 u;
#pragma unroll
            for (int jj = 0; jj < 8; ++jj)
                u[jj] = (_Float16)Ug[g][(size_t)(kc * 32 + hi * 8 + jj) * 512 + unit];
            ufrag[g][kc] = u;
        }
    }

    // ---- staging assignments ----
    // h: thread tid loads ull j -> dwords {j*512 + 2*tid, +1} = row j, units {2t,2t+1}
    const int hu  = 2 * tid;
    const int hkc = hu >> 5, hhi = (hu >> 3) & 3, hjj = hu & 7;   // jj even
    // x: thread tid loads column k=tid of rows 0..7
    const int xkc = tid >> 5, xhi = (tid >> 3) & 3, xjj = tid & 7;
    const float* xcolb = x + (size_t)ig * 8 * 262144 + tid;        // + r*262144 + t*256

    f4 cst = {0.f, 0.f, 0.f, 0.f};   // cell state, C-layout rows hi*4+d

    // ---- prologue: stage x_0 into ldsX ----
    {
        float xv[8];
#pragma unroll
        for (int r = 0; r < 8; ++r) xv[r] = xcolb[(size_t)r * 262144];
#pragma unroll
        for (int r = 0; r < 8; ++r)
            ldsX[(size_t)(xkc * 32 + xhi * 8 + r) * 8 + xjj] = (_Float16)xv[r];
        __syncthreads();
    }

    for (int t = 0; t < 1024; ++t) {
        const int pr = (t + 1) & 1, pw = t & 1;
        const unsigned etag = (unsigned)((t + 1023) & 1023);   // tag of h_{t-1}

        // ---- phase 1: issue x_{t+1} loads (cached; consumed after retry) ----
        float xv[8];
        {
            const float* xc = xcolb + (size_t)((t < 1023) ? t + 1 : t) * 256;
#pragma unroll
            for (int r = 0; r < 8; ++r) xv[r] = xc[(size_t)r * 262144];
        }

        // ---- phase 2: gate-init = bias + x_t @ U (from ldsX) ----
        f4 acc[4];
#pragma unroll
        for (int g = 0; g < 4; ++g) {
            f4 a; a[0] = bias[g]; a[1] = bias[g]; a[2] = bias[g]; a[3] = bias[g];
            acc[g] = a;
        }
#pragma unroll
        for (int kc = 0; kc < 8; ++kc) {
            const h8 xa = *(const h8*)&ldsX[(size_t)(kc * 32 + hi * 8 + r8) * 8];
            acc[0] = __builtin_amdgcn_mfma_f32_16x16x32_f16(xa, ufrag[0][kc], acc[0], 0, 0, 0);
            acc[1] = __builtin_amdgcn_mfma_f32_16x16x32_f16(xa, ufrag[1][kc], acc[1], 0, 0, 0);
            acc[2] = __builtin_amdgcn_mfma_f32_16x16x32_f16(xa, ufrag[2][kc], acc[2], 0, 0, 0);
            acc[3] = __builtin_amdgcn_mfma_f32_16x16x32_f16(xa, ufrag[3][kc], acc[3], 0, 0, 0);
        }

        // ---- phase 3: cooperative tagged h staging (coalesced bypass loads) ----
        const unsigned long long* hpd =
            (const unsigned long long*)(hbuf + (size_t)(pr * 8 + ig) * 4096) + tid;
        unsigned long long q[8];
        int bad;
        do {
#pragma unroll
            for (int j = 0; j < 8; ++j)
                q[j] = __hip_atomic_load(hpd + j * 256, __ATOMIC_RELAXED, __HIP_MEMORY_SCOPE_AGENT);
            unsigned err = 0u;
#pragma unroll
            for (int j = 0; j < 8; ++j) {
                union { unsigned long long q; unsigned u[2]; } v; v.q = q[j];
                err |= (v.u[0] ^ etag) & 1023u;
                err |= (v.u[1] ^ etag) & 1023u;
            }
            const unsigned long long anyb = __ballot(err != 0u);
            if (l == 0) s_err[w] = (anyb != 0ull) ? 1u : 0u;
            __syncthreads();
            bad = (int)(s_err[0] | s_err[1] | s_err[2] | s_err[3]);
            __syncthreads();
        } while (bad);

        // ---- phase 4: h -> fp16 -> ldsH in fragment order (row j, units 2t..2t+1) ----
#pragma unroll
        for (int j = 0; j < 8; ++j) {
            union { unsigned long long q; unsigned u[2]; } v; v.q = q[j];
            union { _Float16 h[2]; unsigned u; } p;
            p.h[0] = (_Float16)__uint_as_float(v.u[0]);
            p.h[1] = (_Float16)__uint_as_float(v.u[1]);
            *(unsigned*)&ldsH[(size_t)(hkc * 32 + hhi * 8 + j) * 8 + hjj] = p.u;
        }
        // ---- phase 5: x_{t+1} -> ldsX ----
#pragma unroll
        for (int r = 0; r < 8; ++r)
            ldsX[(size_t)(xkc * 32 + xhi * 8 + r) * 8 + xjj] = (_Float16)xv[r];
        __syncthreads();

        // ---- phase 6: h_{t-1} @ V from ldsH (canonical b128 reads) ----
#pragma unroll
        for (int kc = 0; kc < 16; ++kc) {
            const h8 a = *(const h8*)&ldsH[(size_t)(kc * 32 + hi * 8 + r8) * 8];
            acc[0] = __builtin_amdgcn_mfma_f32_16x16x32_f16(a, vfrag[0][kc], acc[0], 0, 0, 0);
            acc[1] = __builtin_amdgcn_mfma_f32_16x16x32_f16(a, vfrag[1][kc], acc[1], 0, 0, 0);
            acc[2] = __builtin_amdgcn_mfma_f32_16x16x32_f16(a, vfrag[2][kc], acc[2], 0, 0, 0);
            acc[3] = __builtin_amdgcn_mfma_f32_16x16x32_f16(a, vfrag[3][kc], acc[3], 0, 0, 0);
        }

        // ---- phase 7: elementwise + tagged publish (fire-and-forget) ----
        const unsigned ptag = (unsigned)(t & 1023);
        unsigned pub[4];
#pragma unroll
        for (int d = 0; d < 4; ++d) {
            const float iv = sigm(acc[0][d]);
            const float fv = sigm(acc[1][d]);
            const float gv = tanh_a(acc[2][d]);
            const float ov = sigm(acc[3][d]);
            const float c = fv * cst[d] + iv * gv;
            cst[d] = c;
            const float hv = ov * tanh_a(c);
            pub[d] = (__float_as_uint(hv) & 0xFFFFFC00u) | ptag;
        }
        if (hi < 2) {
            unsigned* hw = hbuf + (size_t)((pw * 8 + ig) * 8 + hi * 4) * 512 + unit;
#pragma unroll
            for (int d = 0; d < 4; ++d)
                __hip_atomic_store(hw + (size_t)d * 512, pub[d],
                                   __ATOMIC_RELAXED, __HIP_MEMORY_SCOPE_AGENT);
        }
    }
}

// ---------------- k_fc: out[b] = h_last[b,:] . fc_w + fc_b ----------------
__global__ __launch_bounds__(64) void k_fc(
    const unsigned* __restrict__ hbuf, const float* __restrict__ fcw,
    const float* __restrict__ fcb, float* __restrict__ out)
{
    const int b = blockIdx.x, l = threadIdx.x;
    // h_1023 lives at parity 1; ig = b>>3, row = b&7; mask the tag bits
    const unsigned* h = hbuf + (size_t)((8 + (b >> 3)) * 8 + (b & 7)) * 512;
    float s = 0.f;
#pragma unroll
    for (int k = 0; k < 8; ++k) {
        const float hv = __uint_as_float(h[l + k * 64] & 0xFFFFFC00u);
        s += hv * fcw[l + k * 64];
    }
    for (int off = 32; off > 0; off >>= 1) s += __shfl_down(s, off, 64);
    if (l == 0) out[b] = s + fcb[0];
}

__global__ __launch_bounds__(64) void k_sentinel(float* out)
{
    out[threadIdx.x] = -777777.0f;   // signature: ws_size too small
}

extern "C" void kernel_launch(void* const* d_in, const int* in_sizes, int n_in,
                              void* d_out, int out_size, void* d_ws, size_t ws_size,
                              hipStream_t stream)
{
    const float* x   = (const float*)d_in[0];
    const float* Ui  = (const float*)d_in[1];
    const float* Vi  = (const float*)d_in[2];
    const float* bi  = (const float*)d_in[3];
    const float* Uf  = (const float*)d_in[4];
    const float* Vf  = (const float*)d_in[5];
    const float* bf  = (const float*)d_in[6];
    const float* Uh  = (const float*)d_in[7];
    const float* Vh  = (const float*)d_in[8];
    const float* bh  = (const float*)d_in[9];
    const float* Uo  = (const float*)d_in[10];
    const float* Vo  = (const float*)d_in[11];
    const float* bo  = (const float*)d_in[12];
    const float* fcw = (const float*)d_in[13];
    const float* fcb = (const float*)d_in[14];
    float* out = (float*)d_out;

    if (ws_size < WS_NEEDED) {
        k_sentinel<<<1, 64, 0, stream>>>(out);
        return;
    }

    unsigned* hbuf = (unsigned*)((char*)d_ws + OFF_HBUF);

    k_init<<<256, 256, 0, stream>>>(hbuf);
    k_rec <<<64,  256, 0, stream>>>(x, Ui, Vi, bi, Uf, Vf, bf, Uh, Vh, bh,
                                    Uo, Vo, bo, hbuf);
    k_fc  <<<64,   64, 0, stream>>>(hbuf, fcw, fcb, out);
}